// Round 1
// baseline (3771.107 us; speedup 1.0000x reference)
//
#include <hip/hip_runtime.h>
#include <hip/hip_bf16.h>

// B=64, S=2048, WIN=50, E=128, H=256, G=4H=1024.
#define B_ 64
#define S_ 2048
#define W_ 50
#define E_ 128
#define H_ 256
#define G_ 1024

typedef unsigned short u16;
typedef unsigned int u32;
typedef unsigned char u8;
typedef unsigned int v4u __attribute__((ext_vector_type(4)));

// Module-global scratch (BSS; d_ws untrusted).
__device__ int g_mode;                          // 0 = bf16 buffers, 1 = fp32 buffers
__device__ u16 g_WihT[E_ * G_];                 // [e][4u+q] = Wih[q*H+u][e]  (bf16)
__device__ u32 g_Wi8[G_ * 64];                  // [u][j][g]: u*256+j*4+g = pack4(Whh[g*256+u][4j..4j+3])
__device__ float g_wscale[G_];                  // per-column dequant: max|W[:,c]| /(127*127), c=4u+g
__device__ u16 g_xg[(size_t)B_ * S_ * G_];      // [b][s][1024] bf16, biases folded (validated)
__device__ float g_hs[(size_t)B_ * S_ * H_];    // [b][s][u] fp32 hidden states (for output head)

__device__ __forceinline__ float b2f(u16 u) {
    union { u32 i; float f; } v;
    v.i = ((u32)u) << 16;
    return v.f;
}
__device__ __forceinline__ u16 f2b(float f) {
    __hip_bfloat16 h = __float2bfloat16(f);
    return *reinterpret_cast<u16*>(&h);
}
__device__ __forceinline__ float ldin(int mode, const void* p, size_t i) {
    return mode ? ((const float*)p)[i] : b2f(((const u16*)p)[i]);
}
__device__ __forceinline__ float clamp30(float x) {
    return fminf(fmaxf(x, -30.0f), 30.0f);
}
__device__ __forceinline__ float sigmoidf_(float x) { return 1.0f / (1.0f + __expf(-x)); }
__device__ __forceinline__ float tanhf_(float x) {
    float e = __expf(2.0f * x);
    return 1.0f - 2.0f / (e + 1.0f);
}
__device__ __forceinline__ int dot4i8(u32 a, u32 b, int acc) {
#if __has_builtin(__builtin_amdgcn_sdot4)
    return __builtin_amdgcn_sdot4(a, b, acc, false);
#else
    acc += (int)(signed char)(a)       * (int)(signed char)(b);
    acc += (int)(signed char)(a >> 8)  * (int)(signed char)(b >> 8);
    acc += (int)(signed char)(a >> 16) * (int)(signed char)(b >> 16);
    acc += (int)(signed char)(a >> 24) * (int)(signed char)(b >> 24);
    return acc;
#endif
}

// ---------- K0: dtype sniffer (validated) ----------
__global__ void sniff_kernel(const u16* __restrict__ wemb) {
    int sane = 0;
    for (int i = 0; i < 2048; ++i) {
        int ex = (wemb[i] >> 7) & 0xFF;
        if (ex == 0 || (ex >= 96 && ex <= 143)) ++sane;
    }
    g_mode = (sane >= 1900) ? 0 : 1;
}

// ---------- K0b: Wih gate-interleaved transpose (for xg_kernel) ----------
__global__ __launch_bounds__(256) void transpose_wih(const void* __restrict__ src) {
    const int mode = g_mode;
    int i = blockIdx.x * 256 + threadIdx.x;          // i = e*G + 4u+q
    int e = i >> 10, r = i & 1023, u = r >> 2, q = r & 3;
    g_WihT[i] = f2b(ldin(mode, src, (size_t)((q << 15) + (u << 7) + e)));
}

// ---------- K0c: Whh -> int8, unit-major quad layout [u][j][g] (validated) ----------
__global__ __launch_bounds__(256) void prep_wi8(const void* __restrict__ src) {
    const int mode = g_mode;
    int c = blockIdx.x * 256 + threadIdx.x;          // c = 4u+g, 0..1023
    int row = ((c & 3) << 8) + (c >> 2);             // gate*256 + unit (validated)
    const size_t base = (size_t)row * H_;
    float m = 0.0f;
    for (int k = 0; k < H_; ++k) m = fmaxf(m, fabsf(ldin(mode, src, base + k)));
    float inv = (m > 0.0f) ? 127.0f / m : 0.0f;
    g_wscale[c] = m / (127.0f * 127.0f);             // w-scale * h-scale(1/127)
    for (int j = 0; j < 64; ++j) {
        u32 pk = 0;
#pragma unroll
        for (int i = 0; i < 4; ++i) {
            int q = (int)rintf(ldin(mode, src, base + 4 * j + i) * inv);
            q = max(-127, min(127, q));
            pk |= ((u32)(q & 0xff)) << (8 * i);
        }
        g_Wi8[(size_t)(c >> 2) * 256 + j * 4 + (c & 3)] = pk;
    }
}

// ---------- K1: fused embedding + input projection (validated round 4) ----------
__global__ __launch_bounds__(256) void xg_kernel(const void* __restrict__ pw,
                                                 const void* __restrict__ Wemb,
                                                 const void* __restrict__ bemb,
                                                 const void* __restrict__ bih,
                                                 const void* __restrict__ bhh) {
    const int mode = g_mode;
    const int t = threadIdx.x;
    const int m0 = blockIdx.x * 16;
    __shared__ float pw16[16][W_ + 2];
    __shared__ float Wl[E_ * 51];
    __shared__ __align__(16) float erow[16][E_];

    for (int i = t; i < E_ * W_; i += 256) {
        int e = i / W_, w = i - e * W_;
        Wl[e * 51 + w] = ldin(mode, Wemb, i);
    }
    for (int i = t; i < 16 * W_; i += 256) {
        int r = i / W_, w = i - r * W_;
        pw16[r][w] = ldin(mode, pw, (size_t)(m0 + r) * W_ + w);
    }
    __syncthreads();

#pragma unroll
    for (int i = 0; i < 8; ++i) {
        int idx = i * 256 + t;
        int r = idx >> 7, e = idx & 127;
        float a = ldin(mode, bemb, e);
        const float* wr = &Wl[e * 51];
#pragma unroll
        for (int w = 0; w < W_; ++w) a = fmaf(pw16[r][w], wr[w], a);
        erow[r][e] = fmaxf(a, 0.0f);
    }
    __syncthreads();

    const int g0 = 4 * t;
    float acc[16][4];
    {
        float b0 = ldin(mode, bih, t) + ldin(mode, bhh, t);
        float b1 = ldin(mode, bih, H_ + t) + ldin(mode, bhh, H_ + t);
        float b2 = ldin(mode, bih, 2 * H_ + t) + ldin(mode, bhh, 2 * H_ + t);
        float b3 = ldin(mode, bih, 3 * H_ + t) + ldin(mode, bhh, 3 * H_ + t);
#pragma unroll
        for (int r = 0; r < 16; ++r) { acc[r][0] = b0; acc[r][1] = b1; acc[r][2] = b2; acc[r][3] = b3; }
    }
    for (int e = 0; e < E_; e += 4) {
        ushort4 w0 = *(const ushort4*)(g_WihT + (size_t)(e + 0) * G_ + g0);
        ushort4 w1 = *(const ushort4*)(g_WihT + (size_t)(e + 1) * G_ + g0);
        ushort4 w2 = *(const ushort4*)(g_WihT + (size_t)(e + 2) * G_ + g0);
        ushort4 w3 = *(const ushort4*)(g_WihT + (size_t)(e + 3) * G_ + g0);
        float f00 = b2f(w0.x), f01 = b2f(w0.y), f02 = b2f(w0.z), f03 = b2f(w0.w);
        float f10 = b2f(w1.x), f11 = b2f(w1.y), f12 = b2f(w1.z), f13 = b2f(w1.w);
        float f20 = b2f(w2.x), f21 = b2f(w2.y), f22 = b2f(w2.z), f23 = b2f(w2.w);
        float f30 = b2f(w3.x), f31 = b2f(w3.y), f32 = b2f(w3.z), f33 = b2f(w3.w);
#pragma unroll
        for (int r = 0; r < 16; ++r) {
            float4 ev = *(const float4*)&erow[r][e];
            acc[r][0] = fmaf(ev.x, f00, acc[r][0]); acc[r][1] = fmaf(ev.x, f01, acc[r][1]);
            acc[r][2] = fmaf(ev.x, f02, acc[r][2]); acc[r][3] = fmaf(ev.x, f03, acc[r][3]);
            acc[r][0] = fmaf(ev.y, f10, acc[r][0]); acc[r][1] = fmaf(ev.y, f11, acc[r][1]);
            acc[r][2] = fmaf(ev.y, f12, acc[r][2]); acc[r][3] = fmaf(ev.y, f13, acc[r][3]);
            acc[r][0] = fmaf(ev.z, f20, acc[r][0]); acc[r][1] = fmaf(ev.z, f21, acc[r][1]);
            acc[r][2] = fmaf(ev.z, f22, acc[r][2]); acc[r][3] = fmaf(ev.z, f23, acc[r][3]);
            acc[r][0] = fmaf(ev.w, f30, acc[r][0]); acc[r][1] = fmaf(ev.w, f31, acc[r][1]);
            acc[r][2] = fmaf(ev.w, f32, acc[r][2]); acc[r][3] = fmaf(ev.w, f33, acc[r][3]);
        }
    }
#pragma unroll
    for (int r = 0; r < 16; ++r) {
        ushort4 sv;
        sv.x = f2b(acc[r][0]); sv.y = f2b(acc[r][1]);
        sv.z = f2b(acc[r][2]); sv.w = f2b(acc[r][3]);
        *(ushort4*)(g_xg + (size_t)(m0 + r) * G_ + g0) = sv;
    }
}

// ---------- K2: recurrence, split-K=4 (1024 thr, 16 waves = 4 waves/SIMD) ----------
// Thread t = (unit u = t>>2, quarter q4 = t&3); holds 16 weight quads (64 VGPRs) for
// k-range [q4*64, q4*64+64). Quarters combine via 2-level shfl_xor (group of 4 lanes
// always within one wave). Barriers are raw s_waitcnt lgkmcnt(0)+s_barrier — NO vmcnt
// drain, so the epoch xg loads and per-step h stores stay in flight across steps.
// h broadcast via 512B double-buffered LDS; producers write single bytes (ds_write_b8)
// instead of 3 dependent shfl_down packs.
__global__ __launch_bounds__(1024)
__attribute__((amdgpu_waves_per_eu(4)))
void lstm_split(const void* __restrict__ h0, const void* __restrict__ c0) {
    const int mode = g_mode;
    const int t = threadIdx.x;
    const int b = blockIdx.x;
    const int u = t >> 2;
    const int q4 = t & 3;

    __shared__ __align__(16) u32 h8[2][H_ / 4];  // double-buffered h (i8), 2x256 B

    // --- 16 weight quads into named v4u via asm (validated pattern) ---
    v4u W00, W01, W02, W03, W04, W05, W06, W07, W08, W09, W10, W11, W12, W13, W14, W15;
    {
        const u32* wp = g_Wi8 + (size_t)t * 64;   // = u*256 + q4*64
        asm volatile(
            "global_load_dwordx4 %0, %16, off\n\t"
            "global_load_dwordx4 %1, %16, off offset:16\n\t"
            "global_load_dwordx4 %2, %16, off offset:32\n\t"
            "global_load_dwordx4 %3, %16, off offset:48\n\t"
            "global_load_dwordx4 %4, %16, off offset:64\n\t"
            "global_load_dwordx4 %5, %16, off offset:80\n\t"
            "global_load_dwordx4 %6, %16, off offset:96\n\t"
            "global_load_dwordx4 %7, %16, off offset:112\n\t"
            "global_load_dwordx4 %8, %16, off offset:128\n\t"
            "global_load_dwordx4 %9, %16, off offset:144\n\t"
            "global_load_dwordx4 %10, %16, off offset:160\n\t"
            "global_load_dwordx4 %11, %16, off offset:176\n\t"
            "global_load_dwordx4 %12, %16, off offset:192\n\t"
            "global_load_dwordx4 %13, %16, off offset:208\n\t"
            "global_load_dwordx4 %14, %16, off offset:224\n\t"
            "global_load_dwordx4 %15, %16, off offset:240\n\t"
            "s_waitcnt vmcnt(0)"
            : "=&v"(W00), "=&v"(W01), "=&v"(W02), "=&v"(W03),
              "=&v"(W04), "=&v"(W05), "=&v"(W06), "=&v"(W07),
              "=&v"(W08), "=&v"(W09), "=&v"(W10), "=&v"(W11),
              "=&v"(W12), "=&v"(W13), "=&v"(W14), "=&v"(W15)
            : "v"(wp));
    }

    const float4 wsc4 = *(const float4*)(g_wscale + 4 * u);
    float c_reg = 0.0f;
    if (q4 == 0) {
        c_reg = ldin(mode, c0, (size_t)b * H_ + u);
        float h = ldin(mode, h0, (size_t)b * H_ + u);
        int q = (int)rintf(fminf(fmaxf(h, -1.0f), 1.0f) * 127.0f) & 0xff;
        ((u8*)h8[0])[u] = (u8)q;
    }
    const u16* xp = g_xg + (size_t)b * S_ * G_ + 4 * u;
    float* hsp = g_hs + (size_t)b * S_ * H_ + u;
    asm volatile("s_waitcnt lgkmcnt(0)\n\t"
                 "s_barrier" ::: "memory");

    for (int s0 = 0; s0 < S_; s0 += 8) {
        // epoch: issue 8 steps of xg loads (q4==0 lanes); no vmcnt drain at barriers,
        // so these stay in flight until each step's activation consumes them.
        ushort4 xq[8];
        if (q4 == 0) {
#pragma unroll
            for (int e = 0; e < 8; ++e)
                xq[e] = *(const ushort4*)(xp + (size_t)(s0 + e) * G_);
        }

#pragma unroll
        for (int e = 0; e < 8; ++e) {
            const int s = s0 + e;
            // stage my k-quarter of h (4 broadcast uint4 reads)
            const uint4* hp = (const uint4*)h8[s & 1] + q4 * 4;
            uint4 h0v = hp[0], h1v = hp[1], h2v = hp[2], h3v = hp[3];

            int ai = 0, af = 0, ag = 0, ao = 0;
#define DOTG(HV, WA, WB, WC, WD)                                              \
            ai = dot4i8(HV.x, WA.x, ai); af = dot4i8(HV.x, WA.y, af);         \
            ag = dot4i8(HV.x, WA.z, ag); ao = dot4i8(HV.x, WA.w, ao);         \
            ai = dot4i8(HV.y, WB.x, ai); af = dot4i8(HV.y, WB.y, af);         \
            ag = dot4i8(HV.y, WB.z, ag); ao = dot4i8(HV.y, WB.w, ao);         \
            ai = dot4i8(HV.z, WC.x, ai); af = dot4i8(HV.z, WC.y, af);         \
            ag = dot4i8(HV.z, WC.z, ag); ao = dot4i8(HV.z, WC.w, ao);         \
            ai = dot4i8(HV.w, WD.x, ai); af = dot4i8(HV.w, WD.y, af);         \
            ag = dot4i8(HV.w, WD.z, ag); ao = dot4i8(HV.w, WD.w, ao);
            DOTG(h0v, W00, W01, W02, W03)
            DOTG(h1v, W04, W05, W06, W07)
            DOTG(h2v, W08, W09, W10, W11)
            DOTG(h3v, W12, W13, W14, W15)
#undef DOTG
            // combine quarters (lanes 4u..4u+3 — always same wave); int adds: exact,
            // order-independent -> numerics identical to split-2 version.
            ai += __shfl_xor(ai, 1, 64);
            af += __shfl_xor(af, 1, 64);
            ag += __shfl_xor(ag, 1, 64);
            ao += __shfl_xor(ao, 1, 64);
            ai += __shfl_xor(ai, 2, 64);
            af += __shfl_xor(af, 2, 64);
            ag += __shfl_xor(ag, 2, 64);
            ao += __shfl_xor(ao, 2, 64);

            if (q4 == 0) {
                float gi = (float)ai * wsc4.x + b2f(xq[e].x);
                float gf = (float)af * wsc4.y + b2f(xq[e].y);
                float gg = (float)ag * wsc4.z + b2f(xq[e].z);
                float go = (float)ao * wsc4.w + b2f(xq[e].w);
                float ii = sigmoidf_(clamp30(gi));
                float ff = sigmoidf_(clamp30(gf));
                float gv = tanhf_(clamp30(gg));
                float oo = sigmoidf_(clamp30(go));
                c_reg = fmaf(ff, c_reg, ii * gv);
                float h = oo * tanhf_(c_reg);
                hsp[(size_t)s * H_] = h;         // fire-and-forget (no vmcnt drain)
                int q = (int)rintf(fminf(fmaxf(h, -1.0f), 1.0f) * 127.0f) & 0xff;
                ((u8*)h8[(s + 1) & 1])[u] = (u8)q;   // single byte write, no pack shfls
            }
            // raw barrier: only LDS ordering needed; keep global loads/stores in flight
            asm volatile("s_waitcnt lgkmcnt(0)\n\t"
                         "s_barrier" ::: "memory");
        }
    }
}

// ---------- K3: output head — one wave per (s,b), fp32 h ----------
__global__ __launch_bounds__(256) void head_kernel(const void* __restrict__ Wout,
                                                   const void* __restrict__ bout,
                                                   void* __restrict__ yv) {
    const int mode = g_mode;
    const int t = threadIdx.x;
    const int idx = blockIdx.x * 4 + (t >> 6);   // (s,b) pair
    const int l = t & 63;
    const int s = idx >> 6, b = idx & 63;
    const float* hb = g_hs + ((size_t)b * S_ + s) * H_ + 4 * l;
    float4 hv = *(const float4*)hb;
    float p = hv.x * ldin(mode, Wout, 4 * l + 0)
            + hv.y * ldin(mode, Wout, 4 * l + 1)
            + hv.z * ldin(mode, Wout, 4 * l + 2)
            + hv.w * ldin(mode, Wout, 4 * l + 3);
#pragma unroll
    for (int off = 32; off > 0; off >>= 1) p += __shfl_down(p, off, 64);
    if (l == 0) {
        float yf = sigmoidf_(clamp30(p + ldin(mode, bout, 0)));
        if (mode) ((float*)yv)[(size_t)s * B_ + b] = yf;
        else      ((u16*)yv)[(size_t)s * B_ + b] = f2b(yf);
    }
}

extern "C" void kernel_launch(void* const* d_in, const int* in_sizes, int n_in,
                              void* d_out, int out_size, void* d_ws, size_t ws_size,
                              hipStream_t stream) {
    const void* pw   = d_in[0];   // [B,S,50]
    const void* Wemb = d_in[1];   // [E,50]
    const void* bemb = d_in[2];   // [E]
    const void* Wih  = d_in[3];   // [G,E]
    const void* Whh  = d_in[4];   // [G,H]
    const void* bih  = d_in[5];   // [G]
    const void* bhh  = d_in[6];   // [G]
    const void* Wout = d_in[7];   // [1,H]
    const void* bout = d_in[8];   // [1]
    const void* h0   = d_in[9];   // [B,H]
    const void* c0   = d_in[10];  // [B,H]
    void* y = d_out;              // [S,B]
    (void)d_ws; (void)ws_size;

    sniff_kernel<<<1, 1, 0, stream>>>((const u16*)Wemb);
    transpose_wih<<<(E_ * G_) / 256, 256, 0, stream>>>(Wih);
    prep_wi8<<<G_ / 256, 256, 0, stream>>>(Whh);
    xg_kernel<<<(B_ * S_) / 16, 256, 0, stream>>>(pw, Wemb, bemb, bih, bhh);
    lstm_split<<<B_, 1024, 0, stream>>>(h0, c0);
    head_kernel<<<(S_ * B_) / 4, 256, 0, stream>>>(Wout, bout, y);
}

// Round 2
// 2812.558 us; speedup vs baseline: 1.3408x; 1.3408x over previous
//
#include <hip/hip_runtime.h>
#include <hip/hip_bf16.h>

// B=64, S=2048, WIN=50, E=128, H=256, G=4H=1024.
#define B_ 64
#define S_ 2048
#define W_ 50
#define E_ 128
#define H_ 256
#define G_ 1024

typedef unsigned short u16;
typedef unsigned int u32;
typedef unsigned char u8;
typedef unsigned int v4u __attribute__((ext_vector_type(4)));

// Module-global scratch (BSS; d_ws untrusted).
__device__ int g_mode;                          // 0 = bf16 buffers, 1 = fp32 buffers
__device__ u16 g_WihT[E_ * G_];                 // [e][4u+q] = Wih[q*H+u][e]  (bf16)
__device__ u32 g_Wi8[G_ * 64];                  // [u][j][g]: u*256+j*4+g = pack4(Whh[g*256+u][4j..4j+3])
__device__ float g_wscale[G_];                  // per-column dequant: max|W[:,c]| /(127*127), c=4u+g
__device__ u16 g_xg[(size_t)B_ * S_ * G_];      // [b][s][1024] bf16, biases folded (validated)
__device__ float g_hs[(size_t)B_ * S_ * H_];    // [b][s][u] fp32 hidden states (for output head)

__device__ __forceinline__ float b2f(u16 u) {
    union { u32 i; float f; } v;
    v.i = ((u32)u) << 16;
    return v.f;
}
__device__ __forceinline__ u16 f2b(float f) {
    __hip_bfloat16 h = __float2bfloat16(f);
    return *reinterpret_cast<u16*>(&h);
}
__device__ __forceinline__ float ldin(int mode, const void* p, size_t i) {
    return mode ? ((const float*)p)[i] : b2f(((const u16*)p)[i]);
}
__device__ __forceinline__ float clamp30(float x) {
    return fminf(fmaxf(x, -30.0f), 30.0f);
}
__device__ __forceinline__ float sigmoidf_(float x) { return 1.0f / (1.0f + __expf(-x)); }
__device__ __forceinline__ float tanhf_(float x) {
    float e = __expf(2.0f * x);
    return 1.0f - 2.0f / (e + 1.0f);
}
__device__ __forceinline__ int dot4i8(u32 a, u32 b, int acc) {
#if __has_builtin(__builtin_amdgcn_sdot4)
    return __builtin_amdgcn_sdot4(a, b, acc, false);
#else
    acc += (int)(signed char)(a)       * (int)(signed char)(b);
    acc += (int)(signed char)(a >> 8)  * (int)(signed char)(b >> 8);
    acc += (int)(signed char)(a >> 16) * (int)(signed char)(b >> 16);
    acc += (int)(signed char)(a >> 24) * (int)(signed char)(b >> 24);
    return acc;
#endif
}

// ---------- K0: dtype sniffer (validated) ----------
__global__ void sniff_kernel(const u16* __restrict__ wemb) {
    int sane = 0;
    for (int i = 0; i < 2048; ++i) {
        int ex = (wemb[i] >> 7) & 0xFF;
        if (ex == 0 || (ex >= 96 && ex <= 143)) ++sane;
    }
    g_mode = (sane >= 1900) ? 0 : 1;
}

// ---------- K0b: Wih gate-interleaved transpose (for xg_kernel) ----------
__global__ __launch_bounds__(256) void transpose_wih(const void* __restrict__ src) {
    const int mode = g_mode;
    int i = blockIdx.x * 256 + threadIdx.x;          // i = e*G + 4u+q
    int e = i >> 10, r = i & 1023, u = r >> 2, q = r & 3;
    g_WihT[i] = f2b(ldin(mode, src, (size_t)((q << 15) + (u << 7) + e)));
}

// ---------- K0c: Whh -> int8, unit-major quad layout [u][j][g] (validated) ----------
__global__ __launch_bounds__(256) void prep_wi8(const void* __restrict__ src) {
    const int mode = g_mode;
    int c = blockIdx.x * 256 + threadIdx.x;          // c = 4u+g, 0..1023
    int row = ((c & 3) << 8) + (c >> 2);             // gate*256 + unit (validated)
    const size_t base = (size_t)row * H_;
    float m = 0.0f;
    for (int k = 0; k < H_; ++k) m = fmaxf(m, fabsf(ldin(mode, src, base + k)));
    float inv = (m > 0.0f) ? 127.0f / m : 0.0f;
    g_wscale[c] = m / (127.0f * 127.0f);             // w-scale * h-scale(1/127)
    for (int j = 0; j < 64; ++j) {
        u32 pk = 0;
#pragma unroll
        for (int i = 0; i < 4; ++i) {
            int q = (int)rintf(ldin(mode, src, base + 4 * j + i) * inv);
            q = max(-127, min(127, q));
            pk |= ((u32)(q & 0xff)) << (8 * i);
        }
        g_Wi8[(size_t)(c >> 2) * 256 + j * 4 + (c & 3)] = pk;
    }
}

// ---------- K1: fused embedding + input projection (validated round 4) ----------
__global__ __launch_bounds__(256) void xg_kernel(const void* __restrict__ pw,
                                                 const void* __restrict__ Wemb,
                                                 const void* __restrict__ bemb,
                                                 const void* __restrict__ bih,
                                                 const void* __restrict__ bhh) {
    const int mode = g_mode;
    const int t = threadIdx.x;
    const int m0 = blockIdx.x * 16;
    __shared__ float pw16[16][W_ + 2];
    __shared__ float Wl[E_ * 51];
    __shared__ __align__(16) float erow[16][E_];

    for (int i = t; i < E_ * W_; i += 256) {
        int e = i / W_, w = i - e * W_;
        Wl[e * 51 + w] = ldin(mode, Wemb, i);
    }
    for (int i = t; i < 16 * W_; i += 256) {
        int r = i / W_, w = i - r * W_;
        pw16[r][w] = ldin(mode, pw, (size_t)(m0 + r) * W_ + w);
    }
    __syncthreads();

#pragma unroll
    for (int i = 0; i < 8; ++i) {
        int idx = i * 256 + t;
        int r = idx >> 7, e = idx & 127;
        float a = ldin(mode, bemb, e);
        const float* wr = &Wl[e * 51];
#pragma unroll
        for (int w = 0; w < W_; ++w) a = fmaf(pw16[r][w], wr[w], a);
        erow[r][e] = fmaxf(a, 0.0f);
    }
    __syncthreads();

    const int g0 = 4 * t;
    float acc[16][4];
    {
        float b0 = ldin(mode, bih, t) + ldin(mode, bhh, t);
        float b1 = ldin(mode, bih, H_ + t) + ldin(mode, bhh, H_ + t);
        float b2 = ldin(mode, bih, 2 * H_ + t) + ldin(mode, bhh, 2 * H_ + t);
        float b3 = ldin(mode, bih, 3 * H_ + t) + ldin(mode, bhh, 3 * H_ + t);
#pragma unroll
        for (int r = 0; r < 16; ++r) { acc[r][0] = b0; acc[r][1] = b1; acc[r][2] = b2; acc[r][3] = b3; }
    }
    for (int e = 0; e < E_; e += 4) {
        ushort4 w0 = *(const ushort4*)(g_WihT + (size_t)(e + 0) * G_ + g0);
        ushort4 w1 = *(const ushort4*)(g_WihT + (size_t)(e + 1) * G_ + g0);
        ushort4 w2 = *(const ushort4*)(g_WihT + (size_t)(e + 2) * G_ + g0);
        ushort4 w3 = *(const ushort4*)(g_WihT + (size_t)(e + 3) * G_ + g0);
        float f00 = b2f(w0.x), f01 = b2f(w0.y), f02 = b2f(w0.z), f03 = b2f(w0.w);
        float f10 = b2f(w1.x), f11 = b2f(w1.y), f12 = b2f(w1.z), f13 = b2f(w1.w);
        float f20 = b2f(w2.x), f21 = b2f(w2.y), f22 = b2f(w2.z), f23 = b2f(w2.w);
        float f30 = b2f(w3.x), f31 = b2f(w3.y), f32 = b2f(w3.z), f33 = b2f(w3.w);
#pragma unroll
        for (int r = 0; r < 16; ++r) {
            float4 ev = *(const float4*)&erow[r][e];
            acc[r][0] = fmaf(ev.x, f00, acc[r][0]); acc[r][1] = fmaf(ev.x, f01, acc[r][1]);
            acc[r][2] = fmaf(ev.x, f02, acc[r][2]); acc[r][3] = fmaf(ev.x, f03, acc[r][3]);
            acc[r][0] = fmaf(ev.y, f10, acc[r][0]); acc[r][1] = fmaf(ev.y, f11, acc[r][1]);
            acc[r][2] = fmaf(ev.y, f12, acc[r][2]); acc[r][3] = fmaf(ev.y, f13, acc[r][3]);
            acc[r][0] = fmaf(ev.z, f20, acc[r][0]); acc[r][1] = fmaf(ev.z, f21, acc[r][1]);
            acc[r][2] = fmaf(ev.z, f22, acc[r][2]); acc[r][3] = fmaf(ev.z, f23, acc[r][3]);
            acc[r][0] = fmaf(ev.w, f30, acc[r][0]); acc[r][1] = fmaf(ev.w, f31, acc[r][1]);
            acc[r][2] = fmaf(ev.w, f32, acc[r][2]); acc[r][3] = fmaf(ev.w, f33, acc[r][3]);
        }
    }
#pragma unroll
    for (int r = 0; r < 16; ++r) {
        ushort4 sv;
        sv.x = f2b(acc[r][0]); sv.y = f2b(acc[r][1]);
        sv.z = f2b(acc[r][2]); sv.w = f2b(acc[r][3]);
        *(ushort4*)(g_xg + (size_t)(m0 + r) * G_ + g0) = sv;
    }
}

// ---------- K2: recurrence, split-K pairs (512 thr, 8 waves, 2 waves/EU) ----------
// Round-0 validated compute skeleton (split-2, 32 weight quads resident in regs,
// shfl_xor(1) half-combine). Round-2 changes are latency-only:
//  (a) raw `s_waitcnt lgkmcnt(0); s_barrier` per step — NO vmcnt drain, so the h
//      store and the epoch xg loads stay in flight across barriers;
//  (b) xg double-buffered one epoch ahead (xqA/xqB, statically indexed) — the
//      ~900cy HBM latency of each epoch's loads hides under the previous epoch;
//  (c) h published via one ds_write_b8 per producer lane instead of 3 dependent
//      shfl_down packs (shorter publish->barrier critical path).
__global__ __launch_bounds__(512)
__attribute__((amdgpu_waves_per_eu(2, 2)))
void lstm_split(const void* __restrict__ h0, const void* __restrict__ c0) {
    const int mode = g_mode;
    const int t = threadIdx.x;
    const int b = blockIdx.x;
    const int u = t >> 1;
    const int half = t & 1;

    __shared__ __align__(16) u32 h8[2][H_ / 4];  // double-buffered h (i8), 2x256 B

    // --- 32 weight quads into named v4u via asm (validated pattern, waitcnt per block) ---
    v4u W00, W01, W02, W03, W04, W05, W06, W07, W08, W09, W10, W11, W12, W13, W14, W15;
    v4u W16, W17, W18, W19, W20, W21, W22, W23, W24, W25, W26, W27, W28, W29, W30, W31;
    {
        const u32* wp = g_Wi8 + (size_t)t * 128;   // = u*256 + half*128
        asm volatile(
            "global_load_dwordx4 %0, %16, off\n\t"
            "global_load_dwordx4 %1, %16, off offset:16\n\t"
            "global_load_dwordx4 %2, %16, off offset:32\n\t"
            "global_load_dwordx4 %3, %16, off offset:48\n\t"
            "global_load_dwordx4 %4, %16, off offset:64\n\t"
            "global_load_dwordx4 %5, %16, off offset:80\n\t"
            "global_load_dwordx4 %6, %16, off offset:96\n\t"
            "global_load_dwordx4 %7, %16, off offset:112\n\t"
            "global_load_dwordx4 %8, %16, off offset:128\n\t"
            "global_load_dwordx4 %9, %16, off offset:144\n\t"
            "global_load_dwordx4 %10, %16, off offset:160\n\t"
            "global_load_dwordx4 %11, %16, off offset:176\n\t"
            "global_load_dwordx4 %12, %16, off offset:192\n\t"
            "global_load_dwordx4 %13, %16, off offset:208\n\t"
            "global_load_dwordx4 %14, %16, off offset:224\n\t"
            "global_load_dwordx4 %15, %16, off offset:240\n\t"
            "s_waitcnt vmcnt(0)"
            : "=&v"(W00), "=&v"(W01), "=&v"(W02), "=&v"(W03),
              "=&v"(W04), "=&v"(W05), "=&v"(W06), "=&v"(W07),
              "=&v"(W08), "=&v"(W09), "=&v"(W10), "=&v"(W11),
              "=&v"(W12), "=&v"(W13), "=&v"(W14), "=&v"(W15)
            : "v"(wp));
        asm volatile(
            "global_load_dwordx4 %0, %16, off offset:256\n\t"
            "global_load_dwordx4 %1, %16, off offset:272\n\t"
            "global_load_dwordx4 %2, %16, off offset:288\n\t"
            "global_load_dwordx4 %3, %16, off offset:304\n\t"
            "global_load_dwordx4 %4, %16, off offset:320\n\t"
            "global_load_dwordx4 %5, %16, off offset:336\n\t"
            "global_load_dwordx4 %6, %16, off offset:352\n\t"
            "global_load_dwordx4 %7, %16, off offset:368\n\t"
            "global_load_dwordx4 %8, %16, off offset:384\n\t"
            "global_load_dwordx4 %9, %16, off offset:400\n\t"
            "global_load_dwordx4 %10, %16, off offset:416\n\t"
            "global_load_dwordx4 %11, %16, off offset:432\n\t"
            "global_load_dwordx4 %12, %16, off offset:448\n\t"
            "global_load_dwordx4 %13, %16, off offset:464\n\t"
            "global_load_dwordx4 %14, %16, off offset:480\n\t"
            "global_load_dwordx4 %15, %16, off offset:496\n\t"
            "s_waitcnt vmcnt(0)"
            : "=&v"(W16), "=&v"(W17), "=&v"(W18), "=&v"(W19),
              "=&v"(W20), "=&v"(W21), "=&v"(W22), "=&v"(W23),
              "=&v"(W24), "=&v"(W25), "=&v"(W26), "=&v"(W27),
              "=&v"(W28), "=&v"(W29), "=&v"(W30), "=&v"(W31)
            : "v"(wp));
    }

    const float4 wsc4 = *(const float4*)(g_wscale + 4 * u);
    float c_reg = (half == 0) ? ldin(mode, c0, (size_t)b * H_ + u) : 0.0f;

    if (t < H_ / 4) {
        u32 pk = 0;
#pragma unroll
        for (int i = 0; i < 4; ++i) {
            float h = ldin(mode, h0, (size_t)b * H_ + 4 * t + i);
            int q = (int)rintf(fminf(fmaxf(h, -1.0f), 1.0f) * 127.0f);
            pk |= ((u32)(q & 0xff)) << (8 * i);
        }
        h8[0][t] = pk;
    }
    const u16* xp = g_xg + (size_t)b * S_ * G_ + 4 * u;
    float* hsp = g_hs + (size_t)b * S_ * H_ + u;

    // preload epoch 0 (consumed by steps 0..7); subsequent epochs prefetched one ahead
    ushort4 xqA[8], xqB[8];
    if (half == 0) {
#pragma unroll
        for (int e = 0; e < 8; ++e)
            xqA[e] = *(const ushort4*)(xp + (size_t)e * G_);
    }
    asm volatile("s_waitcnt lgkmcnt(0)\n\t"
                 "s_barrier" ::: "memory");

#define DOTG(HV, WA, WB, WC, WD)                                              \
            ai = dot4i8(HV.x, WA.x, ai); af = dot4i8(HV.x, WA.y, af);         \
            ag = dot4i8(HV.x, WA.z, ag); ao = dot4i8(HV.x, WA.w, ao);         \
            ai = dot4i8(HV.y, WB.x, ai); af = dot4i8(HV.y, WB.y, af);         \
            ag = dot4i8(HV.y, WB.z, ag); ao = dot4i8(HV.y, WB.w, ao);         \
            ai = dot4i8(HV.z, WC.x, ai); af = dot4i8(HV.z, WC.y, af);         \
            ag = dot4i8(HV.z, WC.z, ag); ao = dot4i8(HV.z, WC.w, ao);         \
            ai = dot4i8(HV.w, WD.x, ai); af = dot4i8(HV.w, WD.y, af);         \
            ag = dot4i8(HV.w, WD.z, ag); ao = dot4i8(HV.w, WD.w, ao);

    // one epoch = 8 steps consuming XQ; prefetches XQN for PSTART (statically indexed)
#define LSTM_EPOCH(S0, XQ, XQN, PSTART)                                       \
    if (half == 0 && (PSTART) < S_) {                                         \
        _Pragma("unroll")                                                     \
        for (int e = 0; e < 8; ++e)                                           \
            XQN[e] = *(const ushort4*)(xp + (size_t)((PSTART) + e) * G_);     \
    }                                                                         \
    _Pragma("unroll")                                                         \
    for (int e = 0; e < 8; ++e) {                                             \
        const int s = (S0) + e;                                               \
        const uint4* hp = (const uint4*)h8[s & 1] + half * 8;                 \
        uint4 h0v = hp[0], h1v = hp[1], h2v = hp[2], h3v = hp[3];             \
        uint4 h4v = hp[4], h5v = hp[5], h6v = hp[6], h7v = hp[7];             \
        int ai = 0, af = 0, ag = 0, ao = 0;                                   \
        DOTG(h0v, W00, W01, W02, W03)                                         \
        DOTG(h1v, W04, W05, W06, W07)                                         \
        DOTG(h2v, W08, W09, W10, W11)                                         \
        DOTG(h3v, W12, W13, W14, W15)                                         \
        DOTG(h4v, W16, W17, W18, W19)                                         \
        DOTG(h5v, W20, W21, W22, W23)                                         \
        DOTG(h6v, W24, W25, W26, W27)                                         \
        DOTG(h7v, W28, W29, W30, W31)                                         \
        ai += __shfl_xor(ai, 1, 64);                                          \
        af += __shfl_xor(af, 1, 64);                                          \
        ag += __shfl_xor(ag, 1, 64);                                          \
        ao += __shfl_xor(ao, 1, 64);                                          \
        if (half == 0) {                                                      \
            float gi = (float)ai * wsc4.x + b2f(XQ[e].x);                     \
            float gf = (float)af * wsc4.y + b2f(XQ[e].y);                     \
            float gg = (float)ag * wsc4.z + b2f(XQ[e].z);                     \
            float go = (float)ao * wsc4.w + b2f(XQ[e].w);                     \
            float ii = sigmoidf_(clamp30(gi));                                \
            float ff = sigmoidf_(clamp30(gf));                                \
            float gv = tanhf_(clamp30(gg));                                   \
            float oo = sigmoidf_(clamp30(go));                                \
            c_reg = fmaf(ff, c_reg, ii * gv);                                 \
            float h = oo * tanhf_(c_reg);                                     \
            int q = (int)rintf(fminf(fmaxf(h, -1.0f), 1.0f) * 127.0f) & 0xff; \
            ((u8*)h8[(s + 1) & 1])[u] = (u8)q;                                \
            hsp[(size_t)s * H_] = h;                                          \
        }                                                                     \
        asm volatile("s_waitcnt lgkmcnt(0)\n\t"                               \
                     "s_barrier" ::: "memory");                               \
    }

    for (int s0 = 0; s0 < S_; s0 += 16) {
        LSTM_EPOCH(s0,     xqA, xqB, s0 + 8)
        LSTM_EPOCH(s0 + 8, xqB, xqA, s0 + 16)
    }
#undef LSTM_EPOCH
#undef DOTG
}

// ---------- K3: output head — one wave per (s,b), fp32 h ----------
__global__ __launch_bounds__(256) void head_kernel(const void* __restrict__ Wout,
                                                   const void* __restrict__ bout,
                                                   void* __restrict__ yv) {
    const int mode = g_mode;
    const int t = threadIdx.x;
    const int idx = blockIdx.x * 4 + (t >> 6);   // (s,b) pair
    const int l = t & 63;
    const int s = idx >> 6, b = idx & 63;
    const float* hb = g_hs + ((size_t)b * S_ + s) * H_ + 4 * l;
    float4 hv = *(const float4*)hb;
    float p = hv.x * ldin(mode, Wout, 4 * l + 0)
            + hv.y * ldin(mode, Wout, 4 * l + 1)
            + hv.z * ldin(mode, Wout, 4 * l + 2)
            + hv.w * ldin(mode, Wout, 4 * l + 3);
#pragma unroll
    for (int off = 32; off > 0; off >>= 1) p += __shfl_down(p, off, 64);
    if (l == 0) {
        float yf = sigmoidf_(clamp30(p + ldin(mode, bout, 0)));
        if (mode) ((float*)yv)[(size_t)s * B_ + b] = yf;
        else      ((u16*)yv)[(size_t)s * B_ + b] = f2b(yf);
    }
}

extern "C" void kernel_launch(void* const* d_in, const int* in_sizes, int n_in,
                              void* d_out, int out_size, void* d_ws, size_t ws_size,
                              hipStream_t stream) {
    const void* pw   = d_in[0];   // [B,S,50]
    const void* Wemb = d_in[1];   // [E,50]
    const void* bemb = d_in[2];   // [E]
    const void* Wih  = d_in[3];   // [G,E]
    const void* Whh  = d_in[4];   // [G,H]
    const void* bih  = d_in[5];   // [G]
    const void* bhh  = d_in[6];   // [G]
    const void* Wout = d_in[7];   // [1,H]
    const void* bout = d_in[8];   // [1]
    const void* h0   = d_in[9];   // [B,H]
    const void* c0   = d_in[10];  // [B,H]
    void* y = d_out;              // [S,B]
    (void)d_ws; (void)ws_size;

    sniff_kernel<<<1, 1, 0, stream>>>((const u16*)Wemb);
    transpose_wih<<<(E_ * G_) / 256, 256, 0, stream>>>(Wih);
    prep_wi8<<<G_ / 256, 256, 0, stream>>>(Whh);
    xg_kernel<<<(B_ * S_) / 16, 256, 0, stream>>>(pw, Wemb, bemb, bih, bhh);
    lstm_split<<<B_, 512, 0, stream>>>(h0, c0);
    head_kernel<<<(S_ * B_) / 4, 256, 0, stream>>>(Wout, bout, y);
}

// Round 3
// 2575.138 us; speedup vs baseline: 1.4644x; 1.0922x over previous
//
#include <hip/hip_runtime.h>
#include <hip/hip_bf16.h>

// B=64, S=2048, WIN=50, E=128, H=256, G=4H=1024.
#define B_ 64
#define S_ 2048
#define W_ 50
#define E_ 128
#define H_ 256
#define G_ 1024

typedef unsigned short u16;
typedef unsigned int u32;
typedef unsigned char u8;
typedef unsigned int v4u __attribute__((ext_vector_type(4)));
typedef __attribute__((ext_vector_type(8))) short short8;   // bf16x8 MFMA frag
typedef __attribute__((ext_vector_type(4))) float f32x4;    // MFMA acc

// Module-global scratch (BSS; d_ws untrusted).
__device__ int g_mode;                          // 0 = bf16 buffers, 1 = fp32 buffers
__device__ u16 g_WA[E_ * G_];                   // Wih in MFMA A-frag order (bf16): ((ct*4+ks)*64+l)*8+j
__device__ float g_bias[G_];                    // bih+bhh, gate-interleaved c = 4u+q
__device__ u32 g_Wi8[G_ * 64];                  // [u][j][g]: u*256+j*4+g = pack4(Whh[g*256+u][4j..4j+3])
__device__ float g_wscale[G_];                  // per-column dequant: max|W[:,c]| /(127*127), c=4u+g
__device__ u16 g_xg[(size_t)B_ * S_ * G_];      // [b][s][1024] bf16, biases folded (validated)
__device__ float g_hs[(size_t)B_ * S_ * H_];    // [b][s][u] fp32 hidden states (for output head)

__device__ __forceinline__ float b2f(u16 u) {
    union { u32 i; float f; } v;
    v.i = ((u32)u) << 16;
    return v.f;
}
__device__ __forceinline__ u16 f2b(float f) {
    __hip_bfloat16 h = __float2bfloat16(f);
    return *reinterpret_cast<u16*>(&h);
}
__device__ __forceinline__ float ldin(int mode, const void* p, size_t i) {
    return mode ? ((const float*)p)[i] : b2f(((const u16*)p)[i]);
}
__device__ __forceinline__ float clamp30(float x) {
    return fminf(fmaxf(x, -30.0f), 30.0f);
}
__device__ __forceinline__ float sigmoidf_(float x) { return 1.0f / (1.0f + __expf(-x)); }
__device__ __forceinline__ float tanhf_(float x) {
    float e = __expf(2.0f * x);
    return 1.0f - 2.0f / (e + 1.0f);
}
__device__ __forceinline__ int dot4i8(u32 a, u32 b, int acc) {
#if __has_builtin(__builtin_amdgcn_sdot4)
    return __builtin_amdgcn_sdot4(a, b, acc, false);
#else
    acc += (int)(signed char)(a)       * (int)(signed char)(b);
    acc += (int)(signed char)(a >> 8)  * (int)(signed char)(b >> 8);
    acc += (int)(signed char)(a >> 16) * (int)(signed char)(b >> 16);
    acc += (int)(signed char)(a >> 24) * (int)(signed char)(b >> 24);
    return acc;
#endif
}

// ---------- K0: dtype sniffer (validated) ----------
__global__ void sniff_kernel(const u16* __restrict__ wemb) {
    int sane = 0;
    for (int i = 0; i < 2048; ++i) {
        int ex = (wemb[i] >> 7) & 0xFF;
        if (ex == 0 || (ex >= 96 && ex <= 143)) ++sane;
    }
    g_mode = (sane >= 1900) ? 0 : 1;
}

// ---------- K0b: Wih -> MFMA A-fragment order ----------
// Consumed as: Af = ((short8*)g_WA)[(ct*4+ks)*64 + l]; element (c,e) with
// c = ct*16 + (l&15), e = ks*32 + (l>>4)*8 + j.  c = 4u+q ↔ Wih row q*256+u.
__global__ __launch_bounds__(256) void prep_wa(const void* __restrict__ src) {
    const int mode = g_mode;
    int i = blockIdx.x * 256 + threadIdx.x;          // dst flat index, 0..131071
    int j = i & 7, l = (i >> 3) & 63, ks = (i >> 9) & 3, ct = i >> 11;
    int c = ct * 16 + (l & 15);
    int e = ks * 32 + (l >> 4) * 8 + j;
    int row = ((c & 3) << 8) + (c >> 2);
    g_WA[i] = f2b(ldin(mode, src, (size_t)row * E_ + e));
}

// ---------- K0c: Whh -> int8, unit-major quad layout [u][j][g]; + gate biases ----------
__global__ __launch_bounds__(256) void prep_wi8(const void* __restrict__ src,
                                                const void* __restrict__ bih,
                                                const void* __restrict__ bhh) {
    const int mode = g_mode;
    int c = blockIdx.x * 256 + threadIdx.x;          // c = 4u+g, 0..1023
    int row = ((c & 3) << 8) + (c >> 2);             // gate*256 + unit (validated)
    g_bias[c] = ldin(mode, bih, row) + ldin(mode, bhh, row);
    const size_t base = (size_t)row * H_;
    float m = 0.0f;
    for (int k = 0; k < H_; ++k) m = fmaxf(m, fabsf(ldin(mode, src, base + k)));
    float inv = (m > 0.0f) ? 127.0f / m : 0.0f;
    g_wscale[c] = m / (127.0f * 127.0f);             // w-scale * h-scale(1/127)
    for (int j = 0; j < 64; ++j) {
        u32 pk = 0;
#pragma unroll
        for (int i = 0; i < 4; ++i) {
            int q = (int)rintf(ldin(mode, src, base + 4 * j + i) * inv);
            q = max(-127, min(127, q));
            pk |= ((u32)(q & 0xff)) << (8 * i);
        }
        g_Wi8[(size_t)(c >> 2) * 256 + j * 4 + (c & 3)] = pk;
    }
}

// ---------- K1: fused embedding (VALU) + input projection (MFMA 16x16x32 bf16) ----------
// Per block: 16 rows (m0..m0+15). Phase A: emb[16][128] = relu(pw @ WembT + bemb),
// stored bf16 in LDS. Phase B: D^T orientation — A = Wih tile (16 c x 32 e, prepacked
// frag-order in g_WA), B = emb^T (32 e x 16 m, ushort8 straight from LDS row l&15).
// D: lane l holds rows c = cbase+4*(l>>4)+reg, col m = m0+(l&15) -> one 8B store/tile.
__global__ __launch_bounds__(256) void xg_mfma(const void* __restrict__ pw,
                                               const void* __restrict__ Wemb,
                                               const void* __restrict__ bemb) {
    const int mode = g_mode;
    const int t = threadIdx.x;
    const int m0 = blockIdx.x * 16;
    __shared__ float pw16[16][W_ + 2];
    __shared__ float Wl[E_ * 51];
    __shared__ __align__(16) u16 embL[16][136];      // bf16, stride 136 (16B-mult, conflict-benign)

    for (int i = t; i < E_ * W_; i += 256) {
        int e = i / W_, w = i - e * W_;
        Wl[e * 51 + w] = ldin(mode, Wemb, i);
    }
    for (int i = t; i < 16 * W_; i += 256) {
        int r = i / W_, w = i - r * W_;
        pw16[r][w] = ldin(mode, pw, (size_t)(m0 + r) * W_ + w);
    }
    __syncthreads();

#pragma unroll
    for (int i = 0; i < 8; ++i) {
        int idx = i * 256 + t;
        int r = idx >> 7, e = idx & 127;
        float a = ldin(mode, bemb, e);
        const float* wr = &Wl[e * 51];
#pragma unroll
        for (int w = 0; w < W_; ++w) a = fmaf(pw16[r][w], wr[w], a);
        embL[r][e] = f2b(fmaxf(a, 0.0f));
    }
    __syncthreads();

    const int l = t & 63;
    const int wv = t >> 6;                           // wave id 0..3 -> 256 columns each
    // B-frags: lane l holds emb[m = l&15][e = ks*32 + (l>>4)*8 + 0..7]; shared by all tiles
    short8 Bf0 = *(const short8*)&embL[l & 15][0 * 32 + (l >> 4) * 8];
    short8 Bf1 = *(const short8*)&embL[l & 15][1 * 32 + (l >> 4) * 8];
    short8 Bf2 = *(const short8*)&embL[l & 15][2 * 32 + (l >> 4) * 8];
    short8 Bf3 = *(const short8*)&embL[l & 15][3 * 32 + (l >> 4) * 8];
    const short8* wa = (const short8*)g_WA;
    const int m = m0 + (l & 15);
#pragma unroll
    for (int tt = 0; tt < 16; ++tt) {
        const int ct = wv * 16 + tt;                 // c-tile index 0..63
        const int cbase = ct * 16;
        const float4 bv = *(const float4*)(g_bias + cbase + 4 * (l >> 4));
        f32x4 acc = {bv.x, bv.y, bv.z, bv.w};
        acc = __builtin_amdgcn_mfma_f32_16x16x32_bf16(wa[(ct * 4 + 0) * 64 + l], Bf0, acc, 0, 0, 0);
        acc = __builtin_amdgcn_mfma_f32_16x16x32_bf16(wa[(ct * 4 + 1) * 64 + l], Bf1, acc, 0, 0, 0);
        acc = __builtin_amdgcn_mfma_f32_16x16x32_bf16(wa[(ct * 4 + 2) * 64 + l], Bf2, acc, 0, 0, 0);
        acc = __builtin_amdgcn_mfma_f32_16x16x32_bf16(wa[(ct * 4 + 3) * 64 + l], Bf3, acc, 0, 0, 0);
        u32 p0 = (u32)f2b(acc[0]) | ((u32)f2b(acc[1]) << 16);
        u32 p1 = (u32)f2b(acc[2]) | ((u32)f2b(acc[3]) << 16);
        uint2 pv; pv.x = p0; pv.y = p1;
        *(uint2*)(g_xg + (size_t)m * G_ + cbase + 4 * (l >> 4)) = pv;
    }
}

// ---------- K2: recurrence, split-K pairs (512 thr, 8 waves, 2 waves/EU) ----------
// Round-3 change: 4-step unrolled body (~6.5KB code, fits L1I; round-2's 16-step
// body was ~26KB and thrashed ifetch) with rolling single-buffer xq prefetch:
// consume xq[e], immediately re-issue xq[e] <- load(s+4) (distance 4 steps covers
// HBM latency). Raw lgkmcnt-only barriers + ds_write_b8 publish kept from round 2.
__global__ __launch_bounds__(512)
__attribute__((amdgpu_waves_per_eu(2, 2)))
void lstm_split(const void* __restrict__ h0, const void* __restrict__ c0) {
    const int mode = g_mode;
    const int t = threadIdx.x;
    const int b = blockIdx.x;
    const int u = t >> 1;
    const int half = t & 1;

    __shared__ __align__(16) u32 h8[2][H_ / 4];  // double-buffered h (i8), 2x256 B

    // --- 32 weight quads into named v4u via asm (validated pattern, waitcnt per block) ---
    v4u W00, W01, W02, W03, W04, W05, W06, W07, W08, W09, W10, W11, W12, W13, W14, W15;
    v4u W16, W17, W18, W19, W20, W21, W22, W23, W24, W25, W26, W27, W28, W29, W30, W31;
    {
        const u32* wp = g_Wi8 + (size_t)t * 128;   // = u*256 + half*128
        asm volatile(
            "global_load_dwordx4 %0, %16, off\n\t"
            "global_load_dwordx4 %1, %16, off offset:16\n\t"
            "global_load_dwordx4 %2, %16, off offset:32\n\t"
            "global_load_dwordx4 %3, %16, off offset:48\n\t"
            "global_load_dwordx4 %4, %16, off offset:64\n\t"
            "global_load_dwordx4 %5, %16, off offset:80\n\t"
            "global_load_dwordx4 %6, %16, off offset:96\n\t"
            "global_load_dwordx4 %7, %16, off offset:112\n\t"
            "global_load_dwordx4 %8, %16, off offset:128\n\t"
            "global_load_dwordx4 %9, %16, off offset:144\n\t"
            "global_load_dwordx4 %10, %16, off offset:160\n\t"
            "global_load_dwordx4 %11, %16, off offset:176\n\t"
            "global_load_dwordx4 %12, %16, off offset:192\n\t"
            "global_load_dwordx4 %13, %16, off offset:208\n\t"
            "global_load_dwordx4 %14, %16, off offset:224\n\t"
            "global_load_dwordx4 %15, %16, off offset:240\n\t"
            "s_waitcnt vmcnt(0)"
            : "=&v"(W00), "=&v"(W01), "=&v"(W02), "=&v"(W03),
              "=&v"(W04), "=&v"(W05), "=&v"(W06), "=&v"(W07),
              "=&v"(W08), "=&v"(W09), "=&v"(W10), "=&v"(W11),
              "=&v"(W12), "=&v"(W13), "=&v"(W14), "=&v"(W15)
            : "v"(wp));
        asm volatile(
            "global_load_dwordx4 %0, %16, off offset:256\n\t"
            "global_load_dwordx4 %1, %16, off offset:272\n\t"
            "global_load_dwordx4 %2, %16, off offset:288\n\t"
            "global_load_dwordx4 %3, %16, off offset:304\n\t"
            "global_load_dwordx4 %4, %16, off offset:320\n\t"
            "global_load_dwordx4 %5, %16, off offset:336\n\t"
            "global_load_dwordx4 %6, %16, off offset:352\n\t"
            "global_load_dwordx4 %7, %16, off offset:368\n\t"
            "global_load_dwordx4 %8, %16, off offset:384\n\t"
            "global_load_dwordx4 %9, %16, off offset:400\n\t"
            "global_load_dwordx4 %10, %16, off offset:416\n\t"
            "global_load_dwordx4 %11, %16, off offset:432\n\t"
            "global_load_dwordx4 %12, %16, off offset:448\n\t"
            "global_load_dwordx4 %13, %16, off offset:464\n\t"
            "global_load_dwordx4 %14, %16, off offset:480\n\t"
            "global_load_dwordx4 %15, %16, off offset:496\n\t"
            "s_waitcnt vmcnt(0)"
            : "=&v"(W16), "=&v"(W17), "=&v"(W18), "=&v"(W19),
              "=&v"(W20), "=&v"(W21), "=&v"(W22), "=&v"(W23),
              "=&v"(W24), "=&v"(W25), "=&v"(W26), "=&v"(W27),
              "=&v"(W28), "=&v"(W29), "=&v"(W30), "=&v"(W31)
            : "v"(wp));
    }

    const float4 wsc4 = *(const float4*)(g_wscale + 4 * u);
    float c_reg = (half == 0) ? ldin(mode, c0, (size_t)b * H_ + u) : 0.0f;

    if (t < H_ / 4) {
        u32 pk = 0;
#pragma unroll
        for (int i = 0; i < 4; ++i) {
            float h = ldin(mode, h0, (size_t)b * H_ + 4 * t + i);
            int q = (int)rintf(fminf(fmaxf(h, -1.0f), 1.0f) * 127.0f);
            pk |= ((u32)(q & 0xff)) << (8 * i);
        }
        h8[0][t] = pk;
    }
    const u16* xp = g_xg + (size_t)b * S_ * G_ + 4 * u;
    float* hsp = g_hs + (size_t)b * S_ * H_ + u;

    // prime rolling prefetch buffer (all lanes load; odd lanes' copies unused but
    // same cache lines -> no extra traffic, no divergence)
    ushort4 xq[4];
#pragma unroll
    for (int e = 0; e < 4; ++e)
        xq[e] = *(const ushort4*)(xp + (size_t)e * G_);

    asm volatile("s_waitcnt lgkmcnt(0)\n\t"
                 "s_barrier" ::: "memory");

#define DOTG(HV, WA, WB, WC, WD)                                              \
            ai = dot4i8(HV.x, WA.x, ai); af = dot4i8(HV.x, WA.y, af);         \
            ag = dot4i8(HV.x, WA.z, ag); ao = dot4i8(HV.x, WA.w, ao);         \
            ai = dot4i8(HV.y, WB.x, ai); af = dot4i8(HV.y, WB.y, af);         \
            ag = dot4i8(HV.y, WB.z, ag); ao = dot4i8(HV.y, WB.w, ao);         \
            ai = dot4i8(HV.z, WC.x, ai); af = dot4i8(HV.z, WC.y, af);         \
            ag = dot4i8(HV.z, WC.z, ag); ao = dot4i8(HV.z, WC.w, ao);         \
            ai = dot4i8(HV.w, WD.x, ai); af = dot4i8(HV.w, WD.y, af);         \
            ag = dot4i8(HV.w, WD.z, ag); ao = dot4i8(HV.w, WD.w, ao);

    for (int s0 = 0; s0 < S_; s0 += 4) {
#pragma unroll
        for (int e = 0; e < 4; ++e) {
            const int s = s0 + e;
            // consume current xq, immediately re-issue for s+4 (rolling prefetch)
            const ushort4 xv = xq[e];
            const int sn = (s + 4 < S_) ? s + 4 : s;
            xq[e] = *(const ushort4*)(xp + (size_t)sn * G_);

            const uint4* hp = (const uint4*)h8[s & 1] + half * 8;
            uint4 h0v = hp[0], h1v = hp[1], h2v = hp[2], h3v = hp[3];
            uint4 h4v = hp[4], h5v = hp[5], h6v = hp[6], h7v = hp[7];

            int ai = 0, af = 0, ag = 0, ao = 0;
            DOTG(h0v, W00, W01, W02, W03)
            DOTG(h1v, W04, W05, W06, W07)
            DOTG(h2v, W08, W09, W10, W11)
            DOTG(h3v, W12, W13, W14, W15)
            DOTG(h4v, W16, W17, W18, W19)
            DOTG(h5v, W20, W21, W22, W23)
            DOTG(h6v, W24, W25, W26, W27)
            DOTG(h7v, W28, W29, W30, W31)

            ai += __shfl_xor(ai, 1, 64);
            af += __shfl_xor(af, 1, 64);
            ag += __shfl_xor(ag, 1, 64);
            ao += __shfl_xor(ao, 1, 64);

            if (half == 0) {
                float gi = (float)ai * wsc4.x + b2f(xv.x);
                float gf = (float)af * wsc4.y + b2f(xv.y);
                float gg = (float)ag * wsc4.z + b2f(xv.z);
                float go = (float)ao * wsc4.w + b2f(xv.w);
                float ii = sigmoidf_(clamp30(gi));
                float ff = sigmoidf_(clamp30(gf));
                float gv = tanhf_(clamp30(gg));
                float oo = sigmoidf_(clamp30(go));
                c_reg = fmaf(ff, c_reg, ii * gv);
                float h = oo * tanhf_(c_reg);
                int q = (int)rintf(fminf(fmaxf(h, -1.0f), 1.0f) * 127.0f) & 0xff;
                ((u8*)h8[(s + 1) & 1])[u] = (u8)q;   // single-byte publish
                hsp[(size_t)s * H_] = h;             // fire-and-forget
            }
            // LDS ordering only; global loads/stores stay in flight
            asm volatile("s_waitcnt lgkmcnt(0)\n\t"
                         "s_barrier" ::: "memory");
        }
    }
#undef DOTG
}

// ---------- K3: output head — one wave per (s,b), fp32 h ----------
__global__ __launch_bounds__(256) void head_kernel(const void* __restrict__ Wout,
                                                   const void* __restrict__ bout,
                                                   void* __restrict__ yv) {
    const int mode = g_mode;
    const int t = threadIdx.x;
    const int idx = blockIdx.x * 4 + (t >> 6);   // (s,b) pair
    const int l = t & 63;
    const int s = idx >> 6, b = idx & 63;
    const float* hb = g_hs + ((size_t)b * S_ + s) * H_ + 4 * l;
    float4 hv = *(const float4*)hb;
    float p = hv.x * ldin(mode, Wout, 4 * l + 0)
            + hv.y * ldin(mode, Wout, 4 * l + 1)
            + hv.z * ldin(mode, Wout, 4 * l + 2)
            + hv.w * ldin(mode, Wout, 4 * l + 3);
#pragma unroll
    for (int off = 32; off > 0; off >>= 1) p += __shfl_down(p, off, 64);
    if (l == 0) {
        float yf = sigmoidf_(clamp30(p + ldin(mode, bout, 0)));
        if (mode) ((float*)yv)[(size_t)s * B_ + b] = yf;
        else      ((u16*)yv)[(size_t)s * B_ + b] = f2b(yf);
    }
}

extern "C" void kernel_launch(void* const* d_in, const int* in_sizes, int n_in,
                              void* d_out, int out_size, void* d_ws, size_t ws_size,
                              hipStream_t stream) {
    const void* pw   = d_in[0];   // [B,S,50]
    const void* Wemb = d_in[1];   // [E,50]
    const void* bemb = d_in[2];   // [E]
    const void* Wih  = d_in[3];   // [G,E]
    const void* Whh  = d_in[4];   // [G,H]
    const void* bih  = d_in[5];   // [G]
    const void* bhh  = d_in[6];   // [G]
    const void* Wout = d_in[7];   // [1,H]
    const void* bout = d_in[8];   // [1]
    const void* h0   = d_in[9];   // [B,H]
    const void* c0   = d_in[10];  // [B,H]
    void* y = d_out;              // [S,B]
    (void)d_ws; (void)ws_size;

    sniff_kernel<<<1, 1, 0, stream>>>((const u16*)Wemb);
    prep_wa<<<(E_ * G_) / 256, 256, 0, stream>>>(Wih);
    prep_wi8<<<G_ / 256, 256, 0, stream>>>(Whh, bih, bhh);
    xg_mfma<<<(B_ * S_) / 16, 256, 0, stream>>>(pw, Wemb, bemb);
    lstm_split<<<B_, 512, 0, stream>>>(h0, c0);
    head_kernel<<<(S_ * B_) / 4, 256, 0, stream>>>(Wout, bout, y);
}